// Round 3
// baseline (971.232 us; speedup 1.0000x reference)
//
#include <hip/hip_runtime.h>

#define B_TOT 32768
#define NDW 14
#define NSTEPS 30

typedef __attribute__((ext_vector_type(8))) short short8;
typedef __attribute__((ext_vector_type(4))) float f32x4;

// ---- workspace byte offsets ----
#define WIH_OFF   0           // enc_wih bf16 plain [512][128]
#define WHH_OFF   131072      // enc_whh bf16 plain [512][128]
#define WD_OFF    262144      // dec_wih+dec_whh bf16 plain [512][128]
#define DWHH_OFF  393216      // dec_whh bf16 plain [512][128]
#define FAW_OFF   524288      // fa_w bf16 plain [128][128]
#define WV_OFF    557056      // pooling wv bf16 plain [128][128]
#define WOUT_OFF  589824      // pool_wout bf16 plain [128][128]
#define QK_OFF    622592      // folded q@wk / sqrt(dh), f32 [4][128]
#define EB_OFF    624640      // enc_bih+enc_bhh f32 [512]
#define DB_OFF    626688      // dec_bih+dec_bhh f32 [512]
#define GIN_OFF   628736      // per-chunk g_in bf16: [ch/16 tiles][14 t][16384 B]

// ---- main kernel LDS (16 KiB total) ----
#define MH0   0        // h buffer 0 (16 rows x 256B, swizzled bf16)
#define MH1   4096     // h buffer 1
#define MSB   8192     // pooling (rf, e) f32 pairs [16][4]          (512 B)
#define MMD   8704     // pooling denom d f32 [16][4]                (256 B)
#define MDW   9216     // decoder head weights f32 [2][128]          (2 KiB)
#define MXB   11264    // ctx tile bf16 (16 rows x 256B)             (4 KiB)
#define MTOT  15360

// ---- pre-pass LDS (160 KiB) ----
#define PGST  0        // staged g_out [8 tiles][16384 B] = 128 KiB
#define PXT   131072   // x / xw tile [128][256B] = 32 KiB

__device__ __forceinline__ unsigned short f2bf(float f) {
  unsigned int u = __float_as_uint(f);
  u += 0x7fffu + ((u >> 16) & 1u);
  return (unsigned short)(u >> 16);
}
__device__ __forceinline__ float bf2f(unsigned short h) {
  return __uint_as_float(((unsigned int)h) << 16);
}
__device__ __forceinline__ float sigmf_(float x) { return __builtin_amdgcn_rcpf(1.f + __expf(-x)); }
__device__ __forceinline__ float tanhf_(float x) { return 1.f - 2.f * __builtin_amdgcn_rcpf(1.f + __expf(2.f * x)); }
__device__ __forceinline__ float softplusf_(float x) { return x > 20.f ? x : __logf(1.f + __expf(x)); }
__device__ __forceinline__ int swz(int row, int bc) { return row * 256 + (bc ^ ((row & 7) << 4)); }
__device__ __forceinline__ f32x4 splat4(float v) { f32x4 r = {v, v, v, v}; return r; }

// ===================== prep: weight conversion / folding =====================
__global__ void hfn_prep(const float* __restrict__ fa_w,
                         const float* __restrict__ enc_wih, const float* __restrict__ enc_whh,
                         const float* __restrict__ enc_bih, const float* __restrict__ enc_bhh,
                         const float* __restrict__ q_tok,
                         const float* __restrict__ pool_win, const float* __restrict__ pool_bin,
                         const float* __restrict__ pool_wout,
                         const float* __restrict__ dec_wih, const float* __restrict__ dec_whh,
                         const float* __restrict__ dec_bih, const float* __restrict__ dec_bhh,
                         char* __restrict__ ws) {
  const int gt = blockIdx.x * 256 + threadIdx.x;
  const int gs = gridDim.x * 256;
  for (int i = gt; i < 65536; i += gs) *(unsigned short*)(ws + WIH_OFF + 2 * i) = f2bf(enc_wih[i]);
  for (int i = gt; i < 65536; i += gs) *(unsigned short*)(ws + WHH_OFF + 2 * i) = f2bf(enc_whh[i]);
  for (int i = gt; i < 65536; i += gs) *(unsigned short*)(ws + WD_OFF + 2 * i) = f2bf(dec_wih[i] + dec_whh[i]);
  for (int i = gt; i < 65536; i += gs) *(unsigned short*)(ws + DWHH_OFF + 2 * i) = f2bf(dec_whh[i]);
  for (int i = gt; i < 16384; i += gs) *(unsigned short*)(ws + FAW_OFF + 2 * i) = f2bf(fa_w[i]);
  for (int i = gt; i < 16384; i += gs) *(unsigned short*)(ws + WV_OFF + 2 * i) = f2bf(pool_win[32768 + i]);
  for (int i = gt; i < 16384; i += gs) *(unsigned short*)(ws + WOUT_OFF + 2 * i) = f2bf(pool_wout[i]);
  for (int i = gt; i < 512; i += gs) *(float*)(ws + EB_OFF + 4 * i) = enc_bih[i] + enc_bhh[i];
  for (int i = gt; i < 512; i += gs) *(float*)(ws + DB_OFF + 4 * i) = dec_bih[i] + dec_bhh[i];
  if (blockIdx.x == 0) {
    __shared__ float q[128];
    const int t = threadIdx.x;
    if (t < 128) {
      float a = 0.f;
      for (int k = 0; k < 128; ++k) a += q_tok[k] * pool_win[t * 128 + k];
      q[t] = a + pool_bin[t];
    }
    __syncthreads();
    for (int j = t; j < 512; j += 256) {
      const int h = j >> 7, kc = j & 127;
      float a = 0.f;
      for (int d = 0; d < 32; ++d) a += q[32 * h + d] * pool_win[(128 + 32 * h + d) * 128 + kc];
      *(float*)(ws + QK_OFF + 4 * j) = a * 0.17677669529663687f;  // bk dropped (softmax-invariant)
    }
  }
}

// ===================== pre-pass: g_in = softmax-attn(x)@wih.T + b for all (b,t) =====================
// grid (ch/128, 14) x 512 thr. Block = (128-row tile, one t). Output layout = main's
// per-thread 32B: tile mt=(row/16)*14+t, addr = mt*16384 + tid_m*32, vals [g0 r0..3][g1][g2][g3].
__global__ __launch_bounds__(512, 2)
void hfn_pre(const float* __restrict__ x14, const float* __restrict__ fa_b,
             char* __restrict__ ws, int base) {
  __shared__ __align__(16) char smem[163840];
  const int tid = threadIdx.x;
  const int w = tid >> 6, lane = tid & 63, l15 = lane & 15, l4 = lane >> 4;
  const int row0 = base + (blockIdx.x << 7);
  const int t = blockIdx.y;

  // wih B-frags: wave w owns gate-cols [64w, 64w+64) -> 16 frags (64 VGPR), held whole block
  short8 bw[4][4];
  float eb4[4];
#pragma unroll
  for (int nt = 0; nt < 4; ++nt) {
#pragma unroll
    for (int kk = 0; kk < 4; ++kk)
      bw[nt][kk] = *(const short8*)(ws + WIH_OFF + (64 * w + 16 * nt + l15) * 256 + 64 * kk + 16 * l4);
    eb4[nt] = *(const float*)(ws + EB_OFF + 4 * (64 * w + 16 * nt + l15));
  }
  float fbias[8];
#pragma unroll
  for (int nt = 0; nt < 8; ++nt) fbias[nt] = fa_b[16 * nt + l15];

  {  // stage x tile (128 rows) f32 -> bf16 swizzled
    const int r = tid >> 2, q = tid & 3;
    const float* src = x14 + ((size_t)(row0 + r) * NDW + t) * 128 + 32 * q;
#pragma unroll
    for (int c = 0; c < 4; ++c) {
      f32x4 v0 = *(const f32x4*)(src + 8 * c);
      f32x4 v1 = *(const f32x4*)(src + 8 * c + 4);
      short8 s;
#pragma unroll
      for (int e = 0; e < 4; ++e) { s[e] = (short)f2bf(v0[e]); s[e + 4] = (short)f2bf(v1[e]); }
      *(short8*)(smem + PXT + swz(r, 64 * q + 16 * c)) = s;
    }
  }
  __syncthreads();
  {  // feature attention in place: wave w handles rows [16w, 16w+16)
    f32x4 patt[8];
#pragma unroll
    for (int nt = 0; nt < 8; ++nt) patt[nt] = splat4(fbias[nt]);
#pragma unroll
    for (int kk = 0; kk < 4; ++kk) {
      const short8 a = *(const short8*)(smem + PXT + swz(16 * w + l15, 64 * kk + 16 * l4));
#pragma unroll
      for (int nt = 0; nt < 8; ++nt) {
        const short8 b = *(const short8*)(ws + FAW_OFF + (16 * nt + l15) * 256 + 64 * kk + 16 * l4);
        patt[nt] = __builtin_amdgcn_mfma_f32_16x16x32_bf16(a, b, patt[nt], 0, 0, 0);
      }
    }
#pragma unroll
    for (int r = 0; r < 4; ++r) {
      float m = patt[0][r];
#pragma unroll
      for (int nt = 1; nt < 8; ++nt) m = fmaxf(m, patt[nt][r]);
      m = fmaxf(m, __shfl_xor(m, 1)); m = fmaxf(m, __shfl_xor(m, 2));
      m = fmaxf(m, __shfl_xor(m, 4)); m = fmaxf(m, __shfl_xor(m, 8));
      float s = 0.f;
#pragma unroll
      for (int nt = 0; nt < 8; ++nt) { const float e = __expf(patt[nt][r] - m); patt[nt][r] = e; s += e; }
      s += __shfl_xor(s, 1); s += __shfl_xor(s, 2); s += __shfl_xor(s, 4); s += __shfl_xor(s, 8);
      const float rs = __builtin_amdgcn_rcpf(s);
      const int row = 16 * w + 4 * l4 + r;
#pragma unroll
      for (int nt = 0; nt < 8; ++nt) {
        const int ad = PXT + swz(row, 2 * (16 * nt + l15));
        const float xv = bf2f(*(const unsigned short*)(smem + ad));
        *(unsigned short*)(smem + ad) = f2bf(patt[nt][r] * rs * xv);
      }
    }
  }
  __syncthreads();
  // gates: per rt (16-row subtile) compute xw@wih.T + eb -> pack to GST in main layout
#pragma unroll
  for (int rt = 0; rt < 8; ++rt) {
    short8 a[4];
#pragma unroll
    for (int kk = 0; kk < 4; ++kk)
      a[kk] = *(const short8*)(smem + PXT + swz(16 * rt + l15, 64 * kk + 16 * l4));
    f32x4 acc[4];
#pragma unroll
    for (int nt = 0; nt < 4; ++nt) acc[nt] = splat4(eb4[nt]);
#pragma unroll
    for (int kk = 0; kk < 4; ++kk)
#pragma unroll
      for (int nt = 0; nt < 4; ++nt)
        acc[nt] = __builtin_amdgcn_mfma_f32_16x16x32_bf16(a[kk], bw[nt][kk], acc[nt], 0, 0, 0);
#pragma unroll
    for (int nt = 0; nt < 4; ++nt) {
      const int gc = 4 * w + nt;  // gate-col block index 0..31
      unsigned int lo = (unsigned int)f2bf(acc[nt][0]) | ((unsigned int)f2bf(acc[nt][1]) << 16);
      unsigned int hi = (unsigned int)f2bf(acc[nt][2]) | ((unsigned int)f2bf(acc[nt][3]) << 16);
      uint2 pk = {lo, hi};
      *(uint2*)(smem + PGST + rt * 16384 + ((gc & 7) << 11) + ((l4 * 16 + l15) << 5) + ((gc >> 3) << 3)) = pk;
    }
  }
  __syncthreads();
  {  // coalesced copy-out: 8 main-tiles of 16 KiB
    const int lt0 = blockIdx.x << 3;
#pragma unroll
    for (int m = 0; m < 8; ++m) {
      char* dst = ws + GIN_OFF + ((size_t)(lt0 + m) * NDW + t) * 16384 + tid * 32;
      *(f32x4*)dst = *(const f32x4*)(smem + PGST + m * 16384 + tid * 32);
      *(f32x4*)(dst + 16) = *(const f32x4*)(smem + PGST + m * 16384 + tid * 32 + 16);
    }
  }
}

// ===================== fused recurrent kernel =====================
// grid ch/16 blocks x 512 thr (8 waves); block owns 16 rows; wave w owns gate-cols [16w,16w+16)
// of each of the 4 gates. Encoder C-init comes from precomputed g_in (bias folded).
__global__ __launch_bounds__(512, 4)
void hfn_main2(const float* __restrict__ pool_bin, const float* __restrict__ pool_bout,
               const float* __restrict__ mu_w, const float* __restrict__ mu_b,
               const float* __restrict__ sig_w, const float* __restrict__ sig_b,
               const float* __restrict__ dmu_w, const float* __restrict__ dmu_b,
               const float* __restrict__ dsig_w, const float* __restrict__ dsig_b,
               char* __restrict__ ws, float* __restrict__ out, int base) {
  __shared__ __align__(16) char sm[MTOT];
  const int tid = threadIdx.x;
  const int w = tid >> 6, lane = tid & 63, l15 = lane & 15, l4 = lane >> 4;
  const int grow0 = base + (blockIdx.x << 4);

  short8 bhh[4][4];
#pragma unroll
  for (int g = 0; g < 4; ++g)
#pragma unroll
    for (int kk = 0; kk < 4; ++kk)
      bhh[g][kk] = *(const short8*)(ws + WHH_OFF + (g * 128 + 16 * w + l15) * 256 + 64 * kk + 16 * l4);
  float creg[4];
#pragma unroll
  for (int r = 0; r < 4; ++r) creg[r] = 0.f;
  *(uint2*)(sm + MH0 + tid * 8) = make_uint2(0, 0);  // h_{-1} = 0

  const char* ginb = ws + GIN_OFF + (size_t)blockIdx.x * NDW * 16384 + tid * 32;
  short8 ga = *(const short8*)ginb;           // prefetch t=0
  short8 gb = *(const short8*)(ginb + 16);
  float mrun = -1e30f, drun = 0.f;
  f32x4 ctx = splat4(0.f);
  __syncthreads();

  // ======================= encoder: 14 steps + fused online pooling =======================
  for (int t = 0; t < NDW; ++t) {
    char* Hr = sm + ((t & 1) ? MH1 : MH0);
    char* Hw = sm + ((t & 1) ? MH0 : MH1);
    const short8 gca = ga, gcb = gb;
    if (t < NDW - 1) {  // prefetch next g_in (hides under compute)
      ga = *(const short8*)(ginb + (t + 1) * 16384);
      gb = *(const short8*)(ginb + (t + 1) * 16384 + 16);
    }
    f32x4 acc[4];
#pragma unroll
    for (int r = 0; r < 4; ++r) {
      acc[0][r] = bf2f((unsigned short)gca[r]);
      acc[1][r] = bf2f((unsigned short)gca[4 + r]);
      acc[2][r] = bf2f((unsigned short)gcb[r]);
      acc[3][r] = bf2f((unsigned short)gcb[4 + r]);
    }
#pragma unroll
    for (int kk = 0; kk < 4; ++kk) {
      const short8 a = *(const short8*)(Hr + swz(l15, 64 * kk + 16 * l4));
#pragma unroll
      for (int g = 0; g < 4; ++g)
        acc[g] = __builtin_amdgcn_mfma_f32_16x16x32_bf16(a, bhh[g][kk], acc[g], 0, 0, 0);
    }
#pragma unroll
    for (int r = 0; r < 4; ++r) {
      const float cn = sigmf_(acc[1][r]) * creg[r] + sigmf_(acc[0][r]) * tanhf_(acc[2][r]);
      creg[r] = cn;
      *(unsigned short*)(Hw + swz(4 * l4 + r, 2 * (16 * w + l15))) = f2bf(sigmf_(acc[3][r]) * tanhf_(cn));
    }
    __syncthreads();
    if (t >= 7) {  // online-softmax pooling update on h_t (t = 7..13)
      {  // scores: thread = (row, head, k-eighth)
        const int rw = tid >> 5, hd = (tid >> 3) & 3, kh = tid & 7;
        const short8 s8a = *(const short8*)(Hw + swz(rw, 32 * kh));
        const short8 s8b = *(const short8*)(Hw + swz(rw, 32 * kh + 16));
        const float* qk = (const float*)(ws + QK_OFF) + hd * 128 + 16 * kh;
        const f32x4 q0 = *(const f32x4*)qk, q1 = *(const f32x4*)(qk + 4);
        const f32x4 q2 = *(const f32x4*)(qk + 8), q3 = *(const f32x4*)(qk + 12);
        float sc = 0.f;
#pragma unroll
        for (int e = 0; e < 4; ++e) {
          sc += bf2f((unsigned short)s8a[e]) * q0[e] + bf2f((unsigned short)s8a[4 + e]) * q1[e];
          sc += bf2f((unsigned short)s8b[e]) * q2[e] + bf2f((unsigned short)s8b[4 + e]) * q3[e];
        }
        sc += __shfl_xor(sc, 1); sc += __shfl_xor(sc, 2); sc += __shfl_xor(sc, 4);
        if (kh == 0) {
          const float mn = fmaxf(mrun, sc);
          const float rf = __expf(mrun - mn);
          const float e = __expf(sc - mn);
          drun = drun * rf + e;
          mrun = mn;
          float2 fe = {rf, e};
          *(float2*)(sm + MSB + (rw * 4 + hd) * 8) = fe;
        }
      }
      __syncthreads();
      {  // V-accum: wave w -> ctx cols [16w,16w+16); v = h_t @ wv.T on the fly
        f32x4 tmp = splat4(0.f);
#pragma unroll
        for (int kk = 0; kk < 4; ++kk) {
          const short8 a = *(const short8*)(Hw + swz(l15, 64 * kk + 16 * l4));
          const short8 bv = *(const short8*)(ws + WV_OFF + (16 * w + l15) * 256 + 64 * kk + 16 * l4);
          tmp = __builtin_amdgcn_mfma_f32_16x16x32_bf16(a, bv, tmp, 0, 0, 0);
        }
#pragma unroll
        for (int r = 0; r < 4; ++r) {
          const float2 fe = *(const float2*)(sm + MSB + ((4 * l4 + r) * 4 + (w >> 1)) * 8);
          ctx[r] = ctx[r] * fe.x + fe.y * tmp[r];
        }
      }
    }
  }
  // h13 is in MH0 (t=13 wrote MH0)

  // ======================= daily heads (h13) =======================
  {
    const int r = tid >> 5, qq = tid & 31, q = qq & 15, hd = qq >> 4;
    const short8 h8 = *(const short8*)(sm + MH0 + swz(r, 16 * q));
    const float* wp = hd ? sig_w : mu_w;
    float s = 0.f;
#pragma unroll
    for (int e = 0; e < 8; ++e) s += bf2f((unsigned short)h8[e]) * wp[8 * q + e];
    s += __shfl_xor(s, 1); s += __shfl_xor(s, 2); s += __shfl_xor(s, 4); s += __shfl_xor(s, 8);
    if (q == 0) {
      if (hd) out[B_TOT + grow0 + r] = softplusf_(s + sig_b[0]);
      else    out[grow0 + r] = s + mu_b[0];
    }
  }
  // keepers publish pooling denominator; stage decoder head weights
  if ((tid & 7) == 0) {
    const int rw = tid >> 5, hd = (tid >> 3) & 3;
    *(float*)(sm + MMD + (rw * 4 + hd) * 4) = drun;
  }
  if (tid < 256) ((float*)(sm + MDW))[tid] = (tid < 128) ? dmu_w[tid] : dsig_w[tid - 128];
  __syncthreads();
  {  // finalize ctx -> bf16 tile MXB
    const float pb = pool_bin[256 + 16 * w + l15];
#pragma unroll
    for (int r = 0; r < 4; ++r) {
      const float d = *(const float*)(sm + MMD + ((4 * l4 + r) * 4 + (w >> 1)) * 4);
      const float v = ctx[r] * __builtin_amdgcn_rcpf(d) + pb;
      *(unsigned short*)(sm + MXB + swz(4 * l4 + r, 2 * (16 * w + l15))) = f2bf(v);
    }
  }
  __syncthreads();
  {  // monthly token = ctx@wout.T + bout -> MH1 (decoder h0)
    f32x4 oa = splat4(pool_bout[16 * w + l15]);
#pragma unroll
    for (int kk = 0; kk < 4; ++kk) {
      const short8 a = *(const short8*)(sm + MXB + swz(l15, 64 * kk + 16 * l4));
      const short8 bo = *(const short8*)(ws + WOUT_OFF + (16 * w + l15) * 256 + 64 * kk + 16 * l4);
      oa = __builtin_amdgcn_mfma_f32_16x16x32_bf16(a, bo, oa, 0, 0, 0);
    }
#pragma unroll
    for (int r = 0; r < 4; ++r)
      *(unsigned short*)(sm + MH1 + swz(4 * l4 + r, 2 * (16 * w + l15))) = f2bf(oa[r]);
  }
  // ======================= decoder: 30 steps =======================
  float bias_s[4];
#pragma unroll
  for (int g = 0; g < 4; ++g) {
    bias_s[g] = *(const float*)(ws + DB_OFF + 4 * (g * 128 + 16 * w + l15));
#pragma unroll
    for (int kk = 0; kk < 4; ++kk)
      bhh[g][kk] = *(const short8*)(ws + DWHH_OFF + (g * 128 + 16 * w + l15) * 256 + 64 * kk + 16 * l4);
  }
#pragma unroll
  for (int r = 0; r < 4; ++r) creg[r] = 0.f;
  const float dmub = dmu_b[0], dsigb = dsig_b[0];
  __syncthreads();
  for (int t = 0; t < NSTEPS; ++t) {
    char* Hr = sm + (((t + 1) & 1) ? MH1 : MH0);  // t=0 -> MH1 (token)
    char* Hw = sm + ((t & 1) ? MH1 : MH0);
    f32x4 acc[4];
#pragma unroll
    for (int g = 0; g < 4; ++g) acc[g] = splat4(bias_s[g]);
#pragma unroll
    for (int kk = 0; kk < 4; ++kk) {
      const short8 a = *(const short8*)(Hr + swz(l15, 64 * kk + 16 * l4));
#pragma unroll
      for (int g = 0; g < 4; ++g)
        acc[g] = __builtin_amdgcn_mfma_f32_16x16x32_bf16(a, bhh[g][kk], acc[g], 0, 0, 0);
    }
#pragma unroll
    for (int r = 0; r < 4; ++r) {
      const float cn = sigmf_(acc[1][r]) * creg[r] + sigmf_(acc[0][r]) * tanhf_(acc[2][r]);
      creg[r] = cn;
      *(unsigned short*)(Hw + swz(4 * l4 + r, 2 * (16 * w + l15))) = f2bf(sigmf_(acc[3][r]) * tanhf_(cn));
    }
    if (t == 0) {  // x_t == h_t for t>=1: switch to combined weights
#pragma unroll
      for (int g = 0; g < 4; ++g)
#pragma unroll
        for (int kk = 0; kk < 4; ++kk)
          bhh[g][kk] = *(const short8*)(ws + WD_OFF + (g * 128 + 16 * w + l15) * 256 + 64 * kk + 16 * l4);
    }
    __syncthreads();
    {  // monthly heads from new h (weights in LDS)
      const int r = tid >> 5, qq = tid & 31, q = qq & 15, hd = qq >> 4;
      const short8 h8 = *(const short8*)(Hw + swz(r, 16 * q));
      const float* wp = (const float*)(sm + MDW) + hd * 128;
      float s = 0.f;
#pragma unroll
      for (int e = 0; e < 8; ++e) s += bf2f((unsigned short)h8[e]) * wp[8 * q + e];
      s += __shfl_xor(s, 1); s += __shfl_xor(s, 2); s += __shfl_xor(s, 4); s += __shfl_xor(s, 8);
      if (q == 0) {
        if (hd) out[32 * B_TOT + (size_t)(grow0 + r) * 30 + t] = softplusf_(s + dsigb);
        else    out[2 * B_TOT + (size_t)(grow0 + r) * 30 + t] = s + dmub;
      }
    }
  }
}

extern "C" void kernel_launch(void* const* d_in, const int* in_sizes, int n_in,
                              void* d_out, int out_size, void* d_ws, size_t ws_size,
                              hipStream_t stream) {
  (void)in_sizes; (void)n_in; (void)out_size;
  const float* x14      = (const float*)d_in[0];
  const float* fa_w     = (const float*)d_in[1];
  const float* fa_b     = (const float*)d_in[2];
  const float* enc_wih  = (const float*)d_in[3];
  const float* enc_whh  = (const float*)d_in[4];
  const float* enc_bih  = (const float*)d_in[5];
  const float* enc_bhh  = (const float*)d_in[6];
  const float* q_tok    = (const float*)d_in[7];
  const float* pool_win = (const float*)d_in[8];
  const float* pool_bin = (const float*)d_in[9];
  const float* pool_wout= (const float*)d_in[10];
  const float* pool_bout= (const float*)d_in[11];
  const float* mu_w     = (const float*)d_in[12];
  const float* mu_b     = (const float*)d_in[13];
  const float* sig_w    = (const float*)d_in[14];
  const float* sig_b    = (const float*)d_in[15];
  const float* dec_wih  = (const float*)d_in[16];
  const float* dec_whh  = (const float*)d_in[17];
  const float* dec_bih  = (const float*)d_in[18];
  const float* dec_bhh  = (const float*)d_in[19];
  const float* dmu_w    = (const float*)d_in[20];
  const float* dmu_b    = (const float*)d_in[21];
  const float* dsig_w   = (const float*)d_in[22];
  const float* dsig_b   = (const float*)d_in[23];
  char* ws = (char*)d_ws;

  hfn_prep<<<dim3(128), dim3(256), 0, stream>>>(fa_w, enc_wih, enc_whh, enc_bih, enc_bhh,
      q_tok, pool_win, pool_bin, pool_wout, dec_wih, dec_whh, dec_bih, dec_bhh, ws);

  // chunk rows so g_in fits ws (8192 rows = 118.07 MB, proven available in round 2;
  // also keeps the g_in blob L3-resident between pre-pass and main).
  int ch = 8192;
  while (ch > 1024 && (size_t)GIN_OFF + (size_t)ch * 14336 > ws_size) ch >>= 1;
  for (int base = 0; base < B_TOT; base += ch) {
    hfn_pre<<<dim3(ch / 128, 14), dim3(512), 0, stream>>>(x14, fa_b, ws, base);
    hfn_main2<<<dim3(ch / 16), dim3(512), 0, stream>>>(pool_bin, pool_bout,
        mu_w, mu_b, sig_w, sig_b, dmu_w, dmu_b, dsig_w, dsig_b, ws, (float*)d_out, base);
  }
}